// Round 4
// baseline (690.399 us; speedup 1.0000x reference)
//
#include <hip/hip_runtime.h>
#include <hip/hip_bf16.h>
#include <math.h>

#define NN 50000
#define EE 800000
#define IND 128
#define OUTD 64
#define NH 4
#define HC 256           // HEADS*OUT_DIM
#define SLOT 64          // max in-degree capacity (Poisson(16))
#define NWIN 8           // one dst window per XCD
#define WINSZ (NN / NWIN)   // 6250
#define BPW 128          // blocks per window (per metapath)

__device__ __forceinline__ float lrelu(float v) { return v > 0.f ? v : 0.2f * v; }
__device__ __forceinline__ unsigned short f2b(float f) {
  __hip_bfloat16 h = __float2bfloat16(f);
  return __builtin_bit_cast(unsigned short, h);
}
__device__ __forceinline__ float b2f(unsigned short u) {
  return __uint_as_float((unsigned)u << 16);
}

// ---------------- XCD-pinned one-pass bucket build ----------------
// window w = blockIdx.x & 7 == XCD id (round-robin dispatch heuristic, m09):
// all writes to window w's slot region come from ONE XCD's L2 -> full-line
// coalescing in L2, writeback ~= payload instead of 8x partial-sector spray.
__global__ __launch_bounds__(256) void k_build(const int* __restrict__ ei0,
                                               const int* __restrict__ ei1,
                                               const int* __restrict__ ei2,
                                               int* __restrict__ deg,
                                               unsigned short* __restrict__ slots) {
  const int w = blockIdx.x & 7;
  const int i0 = blockIdx.x >> 3;       // 0..BPW-1
  const int m = blockIdx.y;
  const int* ei = m == 0 ? ei0 : (m == 1 ? ei1 : ei2);
  const int dlo = w * WINSZ;
  int* degm = deg + m * NN;
  unsigned short* sl = slots + (size_t)m * NN * SLOT;
  for (int e = i0 * 256 + threadIdx.x; e < EE; e += BPW * 256) {
    const int d = ei[EE + e];
    if ((unsigned)(d - dlo) < (unsigned)WINSZ) {
      const int pos = atomicAdd(&degm[d], 1);
      if (pos < SLOT)
        sl[(size_t)d * SLOT + pos] = (unsigned short)ei[e];
    }
  }
}

// ---------------- K1: H16 = bf16(x @ W), layout [n][c][h]; fused logits -----
__global__ __launch_bounds__(256) void k_gemm_fused(const float* __restrict__ x,
                                                    const float* __restrict__ W,
                                                    const float* __restrict__ att_src,
                                                    const float* __restrict__ att_dst,
                                                    unsigned short* __restrict__ H16,
                                                    float* __restrict__ a_src,
                                                    float* __restrict__ a_dst) {
  __shared__ float xs[16 * IND];
  const int tid = threadIdx.x;
  const int row0 = blockIdx.x * 16;   // 3125 blocks exact
  const float4* src = (const float4*)(x + (size_t)row0 * IND);
  float4* dstv = (float4*)xs;
  dstv[tid] = src[tid];
  dstv[tid + 256] = src[tid + 256];
  __syncthreads();
  float acc[16];
#pragma unroll
  for (int r = 0; r < 16; ++r) acc[r] = 0.f;
  const int col = tid;  // col = h*64 + c
  for (int k = 0; k < IND; k += 4) {
    const float w0 = W[(k + 0) * HC + col];
    const float w1 = W[(k + 1) * HC + col];
    const float w2 = W[(k + 2) * HC + col];
    const float w3 = W[(k + 3) * HC + col];
#pragma unroll
    for (int r = 0; r < 16; ++r) {
      const float4 xv = *(const float4*)&xs[r * IND + k];
      acc[r] = fmaf(xv.x, w0, acc[r]);
      acc[r] = fmaf(xv.y, w1, acc[r]);
      acc[r] = fmaf(xv.z, w2, acc[r]);
      acc[r] = fmaf(xv.w, w3, acc[r]);
    }
  }
  const int h = tid >> 6;
  const int c = tid & 63;
  // fused attention logits (fp32): a_src[n][h] = sum_c h*att_src
  const float asv = att_src[col];
  const float adv = att_dst[col];
#pragma unroll
  for (int r = 0; r < 16; ++r) {
    float ps = acc[r] * asv;
    float pd = acc[r] * adv;
    for (int off = 32; off; off >>= 1) {
      ps += __shfl_down(ps, off);
      pd += __shfl_down(pd, off);
    }
    if (c == 0) {
      a_src[(row0 + r) * NH + h] = ps;
      a_dst[(row0 + r) * NH + h] = pd;
    }
  }
  // repack to [n][c][h] via LDS (xs reusable after main loop), store ushort4
  unsigned short* t = (unsigned short*)xs;
  for (int rb = 0; rb < 16; rb += 4) {
    __syncthreads();
#pragma unroll
    for (int r2 = 0; r2 < 4; ++r2)
      t[r2 * 256 + col] = f2b(acc[rb + r2]);
    __syncthreads();
    const int r2 = tid >> 6;
    ushort4 o;
    o.x = t[r2 * 256 + 0 * 64 + c];
    o.y = t[r2 * 256 + 1 * 64 + c];
    o.z = t[r2 * 256 + 2 * 64 + c];
    o.w = t[r2 * 256 + 3 * 64 + c];
    *(ushort4*)&H16[((size_t)(row0 + rb + r2)) * HC + c * 4] = o;
  }
}

// ---------------- K2: slot aggregation, wave per dst, no atomics -----------
// one ushort4 load per edge fetches all 4 heads (layout [n][c][h])
__global__ __launch_bounds__(256) void k_aggr(const unsigned short* __restrict__ slots,
                                              const int* __restrict__ deg,
                                              const unsigned short* __restrict__ H16,
                                              const float* __restrict__ a_src,
                                              const float* __restrict__ a_dst,
                                              const float* __restrict__ bias,
                                              float* __restrict__ z) {
  const int d = blockIdx.x * 4 + (threadIdx.x >> 6);  // 12500 blocks exact
  const int c = threadIdx.x & 63;
  const int nb = min(deg[d], SLOT);
  const float4 adv = *(const float4*)&a_dst[d * NH];
  // self loop
  const float4 asl = *(const float4*)&a_src[d * NH];
  const float e0s = __expf(lrelu(asl.x + adv.x));
  const float e1s = __expf(lrelu(asl.y + adv.y));
  const float e2s = __expf(lrelu(asl.z + adv.z));
  const float e3s = __expf(lrelu(asl.w + adv.w));
  const ushort4 hs = *(const ushort4*)&H16[(size_t)d * HC + c * 4];
  float acc0 = e0s * b2f(hs.x), acc1 = e1s * b2f(hs.y);
  float acc2 = e2s * b2f(hs.z), acc3 = e3s * b2f(hs.w);
  float den0 = e0s, den1 = e1s, den2 = e2s, den3 = e3s;
  int sj = 0;
  float4 ev = make_float4(0.f, 0.f, 0.f, 0.f);
  if (c < nb) {
    sj = slots[(size_t)d * SLOT + c];
    const float4 asv = *(const float4*)&a_src[sj * NH];
    ev.x = __expf(lrelu(asv.x + adv.x));
    ev.y = __expf(lrelu(asv.y + adv.y));
    ev.z = __expf(lrelu(asv.z + adv.z));
    ev.w = __expf(lrelu(asv.w + adv.w));
  }
  for (int j = 0; j < nb; ++j) {
    const int s = __shfl(sj, j, 64);
    const float ex0 = __shfl(ev.x, j, 64);
    const float ex1 = __shfl(ev.y, j, 64);
    const float ex2 = __shfl(ev.z, j, 64);
    const float ex3 = __shfl(ev.w, j, 64);
    const ushort4 hv = *(const ushort4*)&H16[(size_t)s * HC + c * 4];
    acc0 = fmaf(ex0, b2f(hv.x), acc0); den0 += ex0;
    acc1 = fmaf(ex1, b2f(hv.y), acc1); den1 += ex1;
    acc2 = fmaf(ex2, b2f(hv.z), acc2); den2 += ex2;
    acc3 = fmaf(ex3, b2f(hv.w), acc3); den3 += ex3;
  }
  float res = 0.25f * (acc0 / den0 + acc1 / den1 + acc2 / den2 + acc3 / den3);
  res += bias[c];
  z[(size_t)d * OUTD + c] = res > 0.f ? res : __expf(res) - 1.f;
}

// ---------------- K3: semantic attention ----------------
__global__ __launch_bounds__(256) void k_sem(const float* __restrict__ z,
                                             const float* __restrict__ proj_W,
                                             const float* __restrict__ proj_b,
                                             const float* __restrict__ attn_vec,
                                             float* __restrict__ out) {
  __shared__ float zl[4][3][OUTD];
  const int wid = threadIdx.x >> 6;
  const int c = threadIdx.x & 63;
  const int n = blockIdx.x * 4 + wid;   // 12500 blocks exact
#pragma unroll
  for (int m = 0; m < 3; ++m)
    zl[wid][m][c] = z[((size_t)m * NN + n) * OUTD + c];
  __syncthreads();
  float s[3];
#pragma unroll
  for (int m = 0; m < 3; ++m) {
    float acc = proj_b[c];
    for (int k = 0; k < OUTD; ++k)
      acc = fmaf(zl[wid][m][k], proj_W[k * OUTD + c], acc);
    float p = tanhf(acc) * attn_vec[c];
    for (int off = 32; off; off >>= 1) p += __shfl_down(p, off);
    s[m] = __shfl(p, 0, 64);
  }
  const float mx = fmaxf(s[0], fmaxf(s[1], s[2]));
  const float e0 = __expf(s[0] - mx), e1 = __expf(s[1] - mx), e2 = __expf(s[2] - mx);
  const float inv = 1.0f / (e0 + e1 + e2);
  const float b0 = e0 * inv, b1 = e1 * inv, b2 = e2 * inv;
  const float zf = zl[wid][0][c] * b0 + zl[wid][1][c] * b1 + zl[wid][2][c] * b2;
  out[(size_t)n * OUTD + c] = zf;
  if (c < 3) out[(size_t)NN * OUTD + n * 3 + c] = (c == 0 ? b0 : (c == 1 ? b1 : b2));
}

extern "C" void kernel_launch(void* const* d_in, const int* in_sizes, int n_in,
                              void* d_out, int out_size, void* d_ws, size_t ws_size,
                              hipStream_t stream) {
  const float* x = (const float*)d_in[0];
  const int* ei[3];
  const float* W[3];
  const float* as[3];
  const float* ad[3];
  const float* bs[3];

  if (in_sizes[2] != 2 * EE) {
    // dict order: x, (ei,W,att_src,att_dst,bias)*3, proj_W, proj_b, attn_vec
    for (int m = 0; m < 3; ++m) {
      ei[m] = (const int*)d_in[1 + 5 * m];
      W[m]  = (const float*)d_in[2 + 5 * m];
      as[m] = (const float*)d_in[3 + 5 * m];
      ad[m] = (const float*)d_in[4 + 5 * m];
      bs[m] = (const float*)d_in[5 + 5 * m];
    }
  } else {
    // signature order fallback
    for (int m = 0; m < 3; ++m) {
      ei[m] = (const int*)d_in[1 + m];
      W[m]  = (const float*)d_in[4 + m];
      as[m] = (const float*)d_in[7 + m];
      ad[m] = (const float*)d_in[10 + m];
      bs[m] = (const float*)d_in[13 + m];
    }
  }
  const float* proj_W = (const float*)d_in[16];
  const float* proj_b = (const float*)d_in[17];
  const float* attn_vec = (const float*)d_in[18];

  // workspace layout (~85.4 MB)
  char* ws = (char*)d_ws;
  size_t off = 0;
  unsigned short* H16 = (unsigned short*)(ws + off); off += (size_t)NN * HC * 2;       // 25.6 MB
  float* z = (float*)(ws + off);                     off += (size_t)3 * NN * OUTD * 4; // 38.4 MB
  float* a_srcb = (float*)(ws + off);                off += (size_t)NN * NH * 4;       // 0.8 MB
  float* a_dstb = (float*)(ws + off);                off += (size_t)NN * NH * 4;       // 0.8 MB
  int* deg = (int*)(ws + off);                       off += (size_t)3 * NN * 4;        // 0.6 MB
  unsigned short* slots = (unsigned short*)(ws + off); off += (size_t)3 * NN * SLOT * 2; // 19.2 MB

  float* outp = (float*)d_out;

  hipMemsetAsync(deg, 0, (size_t)3 * NN * sizeof(int), stream);
  k_build<<<dim3(NWIN * BPW, 3), 256, 0, stream>>>(ei[0], ei[1], ei[2], deg, slots);

  for (int m = 0; m < 3; ++m) {
    k_gemm_fused<<<NN / 16, 256, 0, stream>>>(x, W[m], as[m], ad[m], H16, a_srcb, a_dstb);
    k_aggr<<<NN / 4, 256, 0, stream>>>(slots + (size_t)m * NN * SLOT, deg + m * NN,
                                       H16, a_srcb, a_dstb, bs[m],
                                       z + (size_t)m * NN * OUTD);
  }
  k_sem<<<NN / 4, 256, 0, stream>>>(z, proj_W, proj_b, attn_vec, outp);
}

// Round 5
// 676.322 us; speedup vs baseline: 1.0208x; 1.0208x over previous
//
#include <hip/hip_runtime.h>
#include <hip/hip_bf16.h>
#include <math.h>

#define NN 50000
#define EE 800000
#define IND 128
#define OUTD 64
#define NH 4
#define HC 256           // HEADS*OUT_DIM
#define SLOT 64          // max in-degree capacity (Poisson(16))
#define NWIN 8           // one dst window per XCD slice
#define WINSZ (NN / NWIN)   // 6250
#define BPW 128          // blocks per window (per metapath)

__device__ __forceinline__ float lrelu(float v) { return v > 0.f ? v : 0.2f * v; }
__device__ __forceinline__ unsigned short f2b(float f) {
  __hip_bfloat16 h = __float2bfloat16(f);
  return __builtin_bit_cast(unsigned short, h);
}
__device__ __forceinline__ float b2f(unsigned short u) {
  return __uint_as_float((unsigned)u << 16);
}

// ---------------- bucket build: NT edge reads keep slot lines L2-resident ---
// window w = blockIdx.x & 7 (round-robin XCD heuristic). Edge-list reads are
// NON-TEMPORAL so they don't evict the window's ~800KB dirty slot region from
// L2 between the ~16 touches of each dst row -> one writeback per line.
__global__ __launch_bounds__(256) void k_build(const int* __restrict__ ei0,
                                               const int* __restrict__ ei1,
                                               const int* __restrict__ ei2,
                                               int* __restrict__ deg,
                                               unsigned short* __restrict__ slots) {
  const int w = blockIdx.x & 7;
  const int i0 = blockIdx.x >> 3;       // 0..BPW-1
  const int m = blockIdx.y;
  const int* ei = m == 0 ? ei0 : (m == 1 ? ei1 : ei2);
  const int dlo = w * WINSZ;
  int* degm = deg + m * NN;
  unsigned short* sl = slots + (size_t)m * NN * SLOT;
  for (int e = i0 * 256 + threadIdx.x; e < EE; e += BPW * 256) {
    const int d = __builtin_nontemporal_load(ei + EE + e);
    if ((unsigned)(d - dlo) < (unsigned)WINSZ) {
      const int s = __builtin_nontemporal_load(ei + e);
      const int pos = atomicAdd(&degm[d], 1);
      if (pos < SLOT)
        sl[(size_t)d * SLOT + pos] = (unsigned short)s;
    }
  }
}

// ---------------- K1: H16 = bf16(x @ W), layout [n][c][h]; fused logits -----
__global__ __launch_bounds__(256) void k_gemm_fused(const float* __restrict__ x,
                                                    const float* __restrict__ W,
                                                    const float* __restrict__ att_src,
                                                    const float* __restrict__ att_dst,
                                                    unsigned short* __restrict__ H16,
                                                    float* __restrict__ a_src,
                                                    float* __restrict__ a_dst) {
  __shared__ float xs[16 * IND];            // 8KB
  __shared__ unsigned short t[16][HC];      // 8KB repack buffer
  const int tid = threadIdx.x;
  const int row0 = blockIdx.x * 16;   // 3125 blocks exact
  const float4* src = (const float4*)(x + (size_t)row0 * IND);
  float4* dstv = (float4*)xs;
  dstv[tid] = src[tid];
  dstv[tid + 256] = src[tid + 256];
  __syncthreads();
  float acc[16];
#pragma unroll
  for (int r = 0; r < 16; ++r) acc[r] = 0.f;
  const int col = tid;  // col = h*64 + c
  for (int k = 0; k < IND; k += 4) {
    const float w0 = W[(k + 0) * HC + col];
    const float w1 = W[(k + 1) * HC + col];
    const float w2 = W[(k + 2) * HC + col];
    const float w3 = W[(k + 3) * HC + col];
#pragma unroll
    for (int r = 0; r < 16; ++r) {
      const float4 xv = *(const float4*)&xs[r * IND + k];
      acc[r] = fmaf(xv.x, w0, acc[r]);
      acc[r] = fmaf(xv.y, w1, acc[r]);
      acc[r] = fmaf(xv.z, w2, acc[r]);
      acc[r] = fmaf(xv.w, w3, acc[r]);
    }
  }
  const int h = tid >> 6;
  const int c = tid & 63;
  // fused attention logits (fp32): a_src[n][h] = sum_c h*att_src
  const float asv = att_src[col];
  const float adv = att_dst[col];
#pragma unroll
  for (int r = 0; r < 16; ++r) {
    float ps = acc[r] * asv;
    float pd = acc[r] * adv;
    for (int off = 32; off; off >>= 1) {
      ps += __shfl_down(ps, off);
      pd += __shfl_down(pd, off);
    }
    if (c == 0) {
      a_src[(row0 + r) * NH + h] = ps;
      a_dst[(row0 + r) * NH + h] = pd;
    }
  }
  // repack to [n][c][h]: one barrier, ushort4 stores
#pragma unroll
  for (int r = 0; r < 16; ++r) t[r][col] = f2b(acc[r]);
  __syncthreads();
  const int r2 = tid >> 6;
#pragma unroll
  for (int g = 0; g < 4; ++g) {
    const int r = g * 4 + r2;
    ushort4 o;
    o.x = t[r][0 * 64 + c];
    o.y = t[r][1 * 64 + c];
    o.z = t[r][2 * 64 + c];
    o.w = t[r][3 * 64 + c];
    *(ushort4*)&H16[(size_t)(row0 + r) * HC + c * 4] = o;
  }
}

// ---------------- K2: slot aggregation, wave per dst, LDS broadcast --------
__global__ __launch_bounds__(256) void k_aggr(const unsigned short* __restrict__ slots,
                                              const int* __restrict__ deg,
                                              const unsigned short* __restrict__ H16,
                                              const float* __restrict__ a_src,
                                              const float* __restrict__ a_dst,
                                              const float* __restrict__ bias,
                                              float* __restrict__ z) {
  __shared__ float evs[4][SLOT][4];   // 16KB: per-wave slot exp values
  __shared__ int soff[4][SLOT];       // 1KB: per-wave H16 byte offsets
  const int wid = threadIdx.x >> 6;
  const int c = threadIdx.x & 63;
  const int d = blockIdx.x * 4 + wid;  // 12500 blocks exact
  const int nb = min(deg[d], SLOT);
  const float4 adv = *(const float4*)&a_dst[d * NH];
  // lane c computes slot c's exp weights; wave-private LDS, no barrier needed
  float4 evr = make_float4(0.f, 0.f, 0.f, 0.f);
  if (c < nb) {
    const int sj = slots[(size_t)d * SLOT + c];
    const float4 asv = *(const float4*)&a_src[sj * NH];
    evr.x = __expf(lrelu(asv.x + adv.x));
    evr.y = __expf(lrelu(asv.y + adv.y));
    evr.z = __expf(lrelu(asv.z + adv.z));
    evr.w = __expf(lrelu(asv.w + adv.w));
    *(float4*)&evs[wid][c][0] = evr;
    soff[wid][c] = sj * (HC * 2);
  }
  // denominators: butterfly reduce of per-lane ev (zeros beyond nb)
  float den0 = evr.x, den1 = evr.y, den2 = evr.z, den3 = evr.w;
#pragma unroll
  for (int mk = 32; mk; mk >>= 1) {
    den0 += __shfl_xor(den0, mk, 64);
    den1 += __shfl_xor(den1, mk, 64);
    den2 += __shfl_xor(den2, mk, 64);
    den3 += __shfl_xor(den3, mk, 64);
  }
  // self loop
  const float4 asl = *(const float4*)&a_src[d * NH];
  const float e0s = __expf(lrelu(asl.x + adv.x));
  const float e1s = __expf(lrelu(asl.y + adv.y));
  const float e2s = __expf(lrelu(asl.z + adv.z));
  const float e3s = __expf(lrelu(asl.w + adv.w));
  den0 += e0s; den1 += e1s; den2 += e2s; den3 += e3s;
  const ushort4 hs = *(const ushort4*)&H16[(size_t)d * HC + c * 4];
  float acc0 = e0s * b2f(hs.x), acc1 = e1s * b2f(hs.y);
  float acc2 = e2s * b2f(hs.z), acc3 = e3s * b2f(hs.w);
  for (int j = 0; j < nb; ++j) {
    const float4 ev4 = *(const float4*)&evs[wid][j][0];   // uniform -> broadcast
    const int off = soff[wid][j];                          // uniform -> broadcast
    const ushort4 hv = *(const ushort4*)((const unsigned char*)H16 + (size_t)off + c * 8);
    acc0 = fmaf(ev4.x, b2f(hv.x), acc0);
    acc1 = fmaf(ev4.y, b2f(hv.y), acc1);
    acc2 = fmaf(ev4.z, b2f(hv.z), acc2);
    acc3 = fmaf(ev4.w, b2f(hv.w), acc3);
  }
  float res = 0.25f * (acc0 / den0 + acc1 / den1 + acc2 / den2 + acc3 / den3);
  res += bias[c];
  z[(size_t)d * OUTD + c] = res > 0.f ? res : __expf(res) - 1.f;
}

// ---------------- K3: semantic attention ----------------
__global__ __launch_bounds__(256) void k_sem(const float* __restrict__ z,
                                             const float* __restrict__ proj_W,
                                             const float* __restrict__ proj_b,
                                             const float* __restrict__ attn_vec,
                                             float* __restrict__ out) {
  __shared__ float zl[4][3][OUTD];
  const int wid = threadIdx.x >> 6;
  const int c = threadIdx.x & 63;
  const int n = blockIdx.x * 4 + wid;   // 12500 blocks exact
#pragma unroll
  for (int m = 0; m < 3; ++m)
    zl[wid][m][c] = z[((size_t)m * NN + n) * OUTD + c];
  __syncthreads();
  float s[3];
#pragma unroll
  for (int m = 0; m < 3; ++m) {
    float acc = proj_b[c];
    for (int k = 0; k < OUTD; ++k)
      acc = fmaf(zl[wid][m][k], proj_W[k * OUTD + c], acc);
    float p = tanhf(acc) * attn_vec[c];
    for (int off = 32; off; off >>= 1) p += __shfl_down(p, off);
    s[m] = __shfl(p, 0, 64);
  }
  const float mx = fmaxf(s[0], fmaxf(s[1], s[2]));
  const float e0 = __expf(s[0] - mx), e1 = __expf(s[1] - mx), e2 = __expf(s[2] - mx);
  const float inv = 1.0f / (e0 + e1 + e2);
  const float b0 = e0 * inv, b1 = e1 * inv, b2 = e2 * inv;
  const float zf = zl[wid][0][c] * b0 + zl[wid][1][c] * b1 + zl[wid][2][c] * b2;
  out[(size_t)n * OUTD + c] = zf;
  if (c < 3) out[(size_t)NN * OUTD + n * 3 + c] = (c == 0 ? b0 : (c == 1 ? b1 : b2));
}

extern "C" void kernel_launch(void* const* d_in, const int* in_sizes, int n_in,
                              void* d_out, int out_size, void* d_ws, size_t ws_size,
                              hipStream_t stream) {
  const float* x = (const float*)d_in[0];
  const int* ei[3];
  const float* W[3];
  const float* as[3];
  const float* ad[3];
  const float* bs[3];

  if (in_sizes[2] != 2 * EE) {
    // dict order: x, (ei,W,att_src,att_dst,bias)*3, proj_W, proj_b, attn_vec
    for (int m = 0; m < 3; ++m) {
      ei[m] = (const int*)d_in[1 + 5 * m];
      W[m]  = (const float*)d_in[2 + 5 * m];
      as[m] = (const float*)d_in[3 + 5 * m];
      ad[m] = (const float*)d_in[4 + 5 * m];
      bs[m] = (const float*)d_in[5 + 5 * m];
    }
  } else {
    // signature order fallback
    for (int m = 0; m < 3; ++m) {
      ei[m] = (const int*)d_in[1 + m];
      W[m]  = (const float*)d_in[4 + m];
      as[m] = (const float*)d_in[7 + m];
      ad[m] = (const float*)d_in[10 + m];
      bs[m] = (const float*)d_in[13 + m];
    }
  }
  const float* proj_W = (const float*)d_in[16];
  const float* proj_b = (const float*)d_in[17];
  const float* attn_vec = (const float*)d_in[18];

  // workspace layout (~85.4 MB)
  char* ws = (char*)d_ws;
  size_t off = 0;
  unsigned short* H16 = (unsigned short*)(ws + off); off += (size_t)NN * HC * 2;       // 25.6 MB
  float* z = (float*)(ws + off);                     off += (size_t)3 * NN * OUTD * 4; // 38.4 MB
  float* a_srcb = (float*)(ws + off);                off += (size_t)NN * NH * 4;       // 0.8 MB
  float* a_dstb = (float*)(ws + off);                off += (size_t)NN * NH * 4;       // 0.8 MB
  int* deg = (int*)(ws + off);                       off += (size_t)3 * NN * 4;        // 0.6 MB
  unsigned short* slots = (unsigned short*)(ws + off); off += (size_t)3 * NN * SLOT * 2; // 19.2 MB

  float* outp = (float*)d_out;

  hipMemsetAsync(deg, 0, (size_t)3 * NN * sizeof(int), stream);
  k_build<<<dim3(NWIN * BPW, 3), 256, 0, stream>>>(ei[0], ei[1], ei[2], deg, slots);

  for (int m = 0; m < 3; ++m) {
    k_gemm_fused<<<NN / 16, 256, 0, stream>>>(x, W[m], as[m], ad[m], H16, a_srcb, a_dstb);
    k_aggr<<<NN / 4, 256, 0, stream>>>(slots + (size_t)m * NN * SLOT, deg + m * NN,
                                       H16, a_srcb, a_dstb, bs[m],
                                       z + (size_t)m * NN * OUTD);
  }
  k_sem<<<NN / 4, 256, 0, stream>>>(z, proj_W, proj_b, attn_vec, outp);
}